// Round 11
// baseline (169.383 us; speedup 1.0000x reference)
//
#include <hip/hip_runtime.h>
#include <hip/hip_bf16.h>
#include <cstdint>

#define NN 2048
#define NH 4
#define NW 64   // mask words per row

typedef __attribute__((ext_vector_type(8))) short bf16x8;
typedef __attribute__((ext_vector_type(4))) float f32x4;
typedef __attribute__((ext_vector_type(4))) int i32x4;
typedef __attribute__((ext_vector_type(4))) unsigned short u16x4;

__device__ __forceinline__ float lrelu(float s) { return s > 0.f ? s : 0.2f * s; }

__device__ __forceinline__ unsigned pk2(float lo, float hi) {
  __hip_bfloat162 h2 = __float22bfloat162_rn(make_float2(lo, hi));
  union { __hip_bfloat162 h; unsigned u; } c; c.h = h2; return c.u;
}
__device__ __forceinline__ unsigned short f2bf1(float f) {
  __hip_bfloat16 h = __float2bfloat16(f);
  union { __hip_bfloat16 h; unsigned short u; } c; c.h = h; return c.u;
}
__device__ __forceinline__ bf16x8 cvt8(f32x4 v0, f32x4 v1) {
  union { unsigned u[4]; bf16x8 v; } r;
  r.u[0] = pk2(v0[0], v0[1]); r.u[1] = pk2(v0[2], v0[3]);
  r.u[2] = pk2(v1[0], v1[1]); r.u[3] = pk2(v1[2], v1[3]);
  return r.v;
}

// Fragment layout for Wh^T (per (b,h) slab of F feats x 2048 nodes):
// short index = (kb*FT + ft)*512 + (feat&15)*8 + gd*128 + e  with node = kb*32+8*gd+e
// -> k-attn lane `lane` loads 16B at frag_base + (kb*FT+ft)*512 + lane*8
//    holding feat = ft*16 + (lane&15), nodes = kb*32 + (lane>>4)*8 .. +7 (B-frag order)

// ---------- kA: proj1 only (512 blocks, 16 rows each) --------------------------
__global__ __launch_bounds__(256) void kA(
    const float* __restrict__ x, const float* __restrict__ W1,
    const float* __restrict__ a1, unsigned short* __restrict__ wht1,
    float* __restrict__ ssrc1, float* __restrict__ G1g, float* __restrict__ G2g) {
  int blk = blockIdx.x;                // 0..511 proj1, 16 rows each
  int rowg = blk * 16;
  int b = rowg >> 11, rloc = rowg & (NN - 1);
  int tid = threadIdx.x, lane = tid & 63, h = tid >> 6;
  int cl = lane & 15, g = lane >> 4;

  const float* xr = x + (size_t)(rowg + cl) * 64 + 8 * g;
  bf16x8 af[2];
#pragma unroll
  for (int ks = 0; ks < 2; ++ks)
    af[ks] = cvt8(*(const f32x4*)(xr + ks * 32), *(const f32x4*)(xr + ks * 32 + 4));

  f32x4 zero = {0.f, 0.f, 0.f, 0.f};
  f32x4 acc[4] = {zero, zero, zero, zero};
#pragma unroll
  for (int ft = 0; ft < 4; ++ft) {
    const float* wr = W1 + (size_t)(h * 64 + ft * 16 + cl) * 64 + 8 * g;
#pragma unroll
    for (int ks = 0; ks < 2; ++ks) {
      bf16x8 bfr = cvt8(*(const f32x4*)(wr + ks * 32), *(const f32x4*)(wr + ks * 32 + 4));
      acc[ft] = __builtin_amdgcn_mfma_f32_16x16x32_bf16(af[ks], bfr, acc[ft], 0, 0, 0);
    }
  }
  // fragment-layout store: node J = rloc+4g+r, feat F = ft*16+cl
  unsigned short* bhb = wht1 + (size_t)(b * NH + h) * 64 * NN;
  int kb = rloc >> 5;
  int gd = ((rloc >> 3) & 2) + (g >> 1);
  int e0 = 4 * (g & 1);
  float ps[4] = {0.f, 0.f, 0.f, 0.f}, pd[4] = {0.f, 0.f, 0.f, 0.f};
#pragma unroll
  for (int ft = 0; ft < 4; ++ft) {
    float as = a1[h * 128 + ft * 16 + cl];
    float ad = a1[h * 128 + 64 + ft * 16 + cl];
    u16x4 w4;
#pragma unroll
    for (int r = 0; r < 4; ++r) {
      float v = acc[ft][r];
      w4[r] = f2bf1(v);
      ps[r] += v * as; pd[r] += v * ad;
    }
    *(u16x4*)(bhb + (size_t)(kb * 4 + ft) * 512 + cl * 8 + gd * 128 + e0) = w4;
  }
#pragma unroll
  for (int r = 0; r < 4; ++r) {
    float s = ps[r], d = pd[r];
    s += __shfl_xor(s, 1); s += __shfl_xor(s, 2); s += __shfl_xor(s, 4); s += __shfl_xor(s, 8);
    d += __shfl_xor(d, 1); d += __shfl_xor(d, 2); d += __shfl_xor(d, 4); d += __shfl_xor(d, 8);
    if (cl == 0) {
      int idx = (b * NH + h) * NN + rloc + 4 * g + r;
      ssrc1[idx] = s;
      G1g[idx] = __expf(d);
      G2g[idx] = __expf(0.2f * d);
    }
  }
}

// ---------- k2: layer-1 attention + inline adj pack.
// block = (b, 16 rows, ALL 4 heads); 8 waves = 4 heads x 2 j-halves.
// adj is read exactly ONCE device-wide here (128 KB/block), packed to LDS,
// and the packed mask is stored to mb for k4. bid&3 = b -> b pinned to 2 XCDs.
__global__ __launch_bounds__(512, 4) void k2_attn1(
    const int* __restrict__ adj, unsigned* __restrict__ mb,
    const unsigned short* __restrict__ wht1, const float* __restrict__ ssrc1,
    const float* __restrict__ G1g, const float* __restrict__ G2g,
    unsigned short* __restrict__ hout) {
  // phase 1: sdm[16][65] 4160 B | sG1[4][2048] 32 KB | sG2[4][2048] 32 KB = 69696 B
  // phase 2 (overlay on sG1): cmb[4][16][68] 17408 B + sden[4][16] 256 B
  __shared__ __align__(16) char smem[69696];
  __shared__ float swmax[8];
  unsigned (*sdm)[65] = (unsigned(*)[65])smem;
  float* sG1 = (float*)(smem + 4160);           // [4][2048]
  float* sG2 = (float*)(smem + 4160 + 32768);   // [4][2048]
  float (*cmb)[16][68] = (float(*)[16][68])(smem + 4160);
  float (*sden)[16] = (float(*)[16])(smem + 4160 + 17408);

  int bid = blockIdx.x;                // 512 = [tile(7 hi)][b(2 lo)]
  int b = bid & 3, tile = bid >> 2;
  int rowblk = tile << 4;              // 16 rows per block
  int t = threadIdx.x, lane = t & 63, w = t >> 6;
  int h = w >> 1, jh = w & 1;          // head, j-half
  int cl = lane & 15, g = lane >> 4, g8 = g * 8;

  { // pack 16 adj rows -> sdm (and write mb for k4). 2 words (64 ints) per thread.
    int r = t >> 5;                    // 16 rows, 32 threads/row
    int w2 = (t & 31) * 2;
    const int* arow = adj + ((size_t)(b * NN) + rowblk + r) * NN;
    unsigned* mrow = mb + ((size_t)(b * NN) + rowblk + r) * NW;
#pragma unroll
    for (int k = 0; k < 2; ++k) {
      int wd = w2 + k;
      const i32x4* ap = (const i32x4*)(arow + wd * 32);
      i32x4 v0 = __builtin_nontemporal_load(ap + 0);
      i32x4 v1 = __builtin_nontemporal_load(ap + 1);
      i32x4 v2 = __builtin_nontemporal_load(ap + 2);
      i32x4 v3 = __builtin_nontemporal_load(ap + 3);
      i32x4 v4 = __builtin_nontemporal_load(ap + 4);
      i32x4 v5 = __builtin_nontemporal_load(ap + 5);
      i32x4 v6 = __builtin_nontemporal_load(ap + 6);
      i32x4 v7 = __builtin_nontemporal_load(ap + 7);
      unsigned word = 0;
#pragma unroll
      for (int j = 0; j < 4; ++j) {
        word |= ((unsigned)(v0[j] != 0)) << (0 + j);
        word |= ((unsigned)(v1[j] != 0)) << (4 + j);
        word |= ((unsigned)(v2[j] != 0)) << (8 + j);
        word |= ((unsigned)(v3[j] != 0)) << (12 + j);
        word |= ((unsigned)(v4[j] != 0)) << (16 + j);
        word |= ((unsigned)(v5[j] != 0)) << (20 + j);
        word |= ((unsigned)(v6[j] != 0)) << (24 + j);
        word |= ((unsigned)(v7[j] != 0)) << (28 + j);
      }
      sdm[r][wd] = word;
      mrow[wd] = word;                 // k4 consumes this
    }
  }
  { // stage this wave's head-half of G1/G2 (1024 floats each) + partial max
    const f32x4* g1p = (const f32x4*)(G1g + (size_t)(b * NH + h) * NN) + jh * 256;
    const f32x4* g2p = (const f32x4*)(G2g + (size_t)(b * NH + h) * NN) + jh * 256;
    f32x4* d1 = (f32x4*)(sG1 + h * NN) + jh * 256;
    f32x4* d2 = (f32x4*)(sG2 + h * NN) + jh * 256;
    float gmx = 0.f;
#pragma unroll
    for (int it = 0; it < 4; ++it) {
      f32x4 v = g1p[it * 64 + lane];
      d1[it * 64 + lane] = v;
      d2[it * 64 + lane] = g2p[it * 64 + lane];
      gmx = fmaxf(fmaxf(gmx, v[0]), fmaxf(v[1], fmaxf(v[2], v[3])));
    }
    gmx = fmaxf(gmx, __shfl_xor(gmx, 1));  gmx = fmaxf(gmx, __shfl_xor(gmx, 2));
    gmx = fmaxf(gmx, __shfl_xor(gmx, 4));  gmx = fmaxf(gmx, __shfl_xor(gmx, 8));
    gmx = fmaxf(gmx, __shfl_xor(gmx, 16)); gmx = fmaxf(gmx, __shfl_xor(gmx, 32));
    if (lane == 0) swmax[w] = gmx;
  }
  float s = ssrc1[(size_t)(b * NH + h) * NN + rowblk + cl];
  __syncthreads();
  float mxv = fmaxf(swmax[h * 2], swmax[h * 2 + 1]);   // head-wide max of G1
  float logMx = __logf(mxv);
  float m = lrelu(s + logMx);          // valid per-row softmax shift (upper bound)
  float F1 = __expf(s - m), F2 = __expf(0.2f * s - m);

  short onev = (cl == 0) ? (short)0x3F80 : (short)0;
  bf16x8 ones = {onev, onev, onev, onev, onev, onev, onev, onev};
  f32x4 zero = {0.f, 0.f, 0.f, 0.f};
  f32x4 acc[4] = {zero, zero, zero, zero};
  f32x4 acc1 = zero;                   // denominator via ones column
  const unsigned short* fbase = wht1 + (size_t)(b * NH + h) * 64 * NN + lane * 8;
  const float* gh1 = sG1 + h * NN;
  const float* gh2 = sG2 + h * NN;
  int kb0 = jh * 32;

  bf16x8 curf[4], nxtf[4];
#pragma unroll
  for (int ft = 0; ft < 4; ++ft)
    curf[ft] = *(const bf16x8*)(fbase + (size_t)(kb0 * 4 + ft) * 512);

  for (int i = 0; i < 32; ++i) {
    int kb = kb0 + i;
    if (i < 31) {                      // prefetch next iteration's fragments
#pragma unroll
      for (int ft = 0; ft < 4; ++ft)
        nxtf[ft] = *(const bf16x8*)(fbase + (size_t)((kb + 1) * 4 + ft) * 512);
    }
    unsigned by = (sdm[cl][kb] >> g8) & 0xFFu;
    int j0 = kb * 32 + g8;
    f32x4 g1a = *(const f32x4*)(gh1 + j0);
    f32x4 g1b = *(const f32x4*)(gh1 + j0 + 4);
    f32x4 g2a = *(const f32x4*)(gh2 + j0);
    f32x4 g2b = *(const f32x4*)(gh2 + j0 + 4);
    float wv[8];
#pragma unroll
    for (int e = 0; e < 8; ++e) {
      float g1 = (e < 4) ? g1a[e] : g1b[e - 4];
      float g2 = (e < 4) ? g2a[e] : g2b[e - 4];
      float v = fmaxf(F1 * g1, F2 * g2);   // exp(lrelu(s+t)-m), branch-free
      wv[e] = ((by >> e) & 1u) ? v : 0.f;
    }
    union { unsigned u[4]; bf16x8 v; } pa;
    pa.u[0] = pk2(wv[0], wv[1]); pa.u[1] = pk2(wv[2], wv[3]);
    pa.u[2] = pk2(wv[4], wv[5]); pa.u[3] = pk2(wv[6], wv[7]);
#pragma unroll
    for (int ft = 0; ft < 4; ++ft)
      acc[ft] = __builtin_amdgcn_mfma_f32_16x16x32_bf16(pa.v, curf[ft], acc[ft], 0, 0, 0);
    acc1 = __builtin_amdgcn_mfma_f32_16x16x32_bf16(pa.v, ones, acc1, 0, 0, 0);
#pragma unroll
    for (int ft = 0; ft < 4; ++ft) curf[ft] = nxtf[ft];
  }
  __syncthreads();                     // all phase-1 LDS reads done; overlay safe
  if (jh == 1) {
#pragma unroll
    for (int ft = 0; ft < 4; ++ft)
#pragma unroll
      for (int r = 0; r < 4; ++r)
        cmb[h][4 * g + r][ft * 16 + cl] = acc[ft][r];
    if (cl == 0) {
#pragma unroll
      for (int r = 0; r < 4; ++r) sden[h][4 * g + r] = acc1[r];
    }
  }
  __syncthreads();
  if (jh == 0) {
#pragma unroll
    for (int r = 0; r < 4; ++r) {
      int rowm = 4 * g + r;
      float dself = __shfl(acc1[r], lane & 48);   // denom col 0 lives at cl==0
      float inv = 1.f / (dself + sden[h][rowm]);
      unsigned short* dst = hout + (size_t)(b * NN + rowblk + rowm) * 256 + h * 64;
#pragma unroll
      for (int ft = 0; ft < 4; ++ft) {
        float v = (acc[ft][r] + cmb[h][rowm][ft * 16 + cl]) * inv;
        v = v > 0.f ? v : (__expf(v) - 1.f);      // ELU
        dst[ft * 16 + cl] = f2bf1(v);             // bf16 (k3 rounds here anyway)
      }
    }
  }
}

// ---------- k3: Wh2 = h @ W2^T via MFMA split-K; frag-layout store + scores ----
__global__ __launch_bounds__(256) void k3_proj2(
    const unsigned short* __restrict__ hin, const float* __restrict__ W2,
    const float* __restrict__ a2, unsigned short* __restrict__ wh2t,
    float* __restrict__ ssrc2, float* __restrict__ G1o, float* __restrict__ G2o) {
  __shared__ float cmb[4][16][33];
  int blk = blockIdx.x;                 // 512: 16 rows each
  int b = blk >> 7, rowbase = (blk & 127) << 4;
  int t = threadIdx.x, lane = t & 63, w = t >> 6;
  int cl = lane & 15, g = lane >> 4;
  int k0 = w * 64;                      // K split across 4 waves

  const unsigned short* hr = hin + (size_t)(b * NN + rowbase + cl) * 256 + k0 + 8 * g;
  bf16x8 af[2];
#pragma unroll
  for (int ks = 0; ks < 2; ++ks)
    af[ks] = *(const bf16x8*)(hr + ks * 32);       // bf16 direct A-fragment

  f32x4 zero = {0.f, 0.f, 0.f, 0.f};
  f32x4 acc[2] = {zero, zero};
#pragma unroll
  for (int ft = 0; ft < 2; ++ft) {
    const float* wr = W2 + (size_t)(ft * 16 + cl) * 256 + k0 + 8 * g;
#pragma unroll
    for (int ks = 0; ks < 2; ++ks) {
      bf16x8 bfr = cvt8(*(const f32x4*)(wr + ks * 32), *(const f32x4*)(wr + ks * 32 + 4));
      acc[ft] = __builtin_amdgcn_mfma_f32_16x16x32_bf16(af[ks], bfr, acc[ft], 0, 0, 0);
    }
  }
#pragma unroll
  for (int ft = 0; ft < 2; ++ft)
#pragma unroll
    for (int r = 0; r < 4; ++r)
      cmb[w][4 * g + r][ft * 16 + cl] = acc[ft][r];
  __syncthreads();

  int row = t >> 4, c0 = t & 15;
  float v0 = cmb[0][row][c0] + cmb[1][row][c0] + cmb[2][row][c0] + cmb[3][row][c0];
  float v1 = cmb[0][row][c0 + 16] + cmb[1][row][c0 + 16] + cmb[2][row][c0 + 16] + cmb[3][row][c0 + 16];
  float ps = v0 * a2[c0] + v1 * a2[c0 + 16];
  float pd = v0 * a2[32 + c0] + v1 * a2[32 + c0 + 16];
  ps += __shfl_xor(ps, 1); ps += __shfl_xor(ps, 2); ps += __shfl_xor(ps, 4); ps += __shfl_xor(ps, 8);
  pd += __shfl_xor(pd, 1); pd += __shfl_xor(pd, 2); pd += __shfl_xor(pd, 4); pd += __shfl_xor(pd, 8);
  if (c0 == 0) {
    int idx = b * NN + rowbase + row;
    ssrc2[idx] = ps;
    G1o[idx] = __expf(pd);
    G2o[idx] = __expf(0.2f * pd);
  }
  cmb[0][row][c0] = v0;
  cmb[0][row][c0 + 16] = v1;
  __syncthreads();
  // fragment-layout bf16 store: feat = col, nodes J = rowbase + 2*rg + {0,1}
  int col = t >> 3, rg = t & 7;
  unsigned pk = pk2(cmb[0][2 * rg][col], cmb[0][2 * rg + 1][col]);
  int kb2 = rowbase >> 5;
  int gd = ((rowbase >> 3) & 2) + (rg >> 2);
  size_t off = (size_t)(kb2 * 2 + (col >> 4)) * 512 + (col & 15) * 8 + gd * 128 + 2 * (rg & 3);
  *(unsigned*)(wh2t + (size_t)b * 32 * NN + off) = pk;
}

// ---------- k4: layer-2 attention. 512 blocks x 16 rows; 8 waves = 8 j-eighths
__global__ __launch_bounds__(512) void k4_attn2(
    const unsigned short* __restrict__ wh2t, const float* __restrict__ ssrc2,
    const float* __restrict__ G1o, const float* __restrict__ G2o,
    const unsigned* __restrict__ mb, float* __restrict__ outp) {
  // phase 1: sdm[16][65] 4160 B | sG1 8 KB | sG2 8 KB = 20544 B
  // phase 2 (overlay): cmb[7][16][36] 16128 B + sden[7][16] 448 B = 16576 B
  __shared__ __align__(16) char smem[20608];
  __shared__ float swmax[8];
  unsigned (*sdm)[65] = (unsigned(*)[65])smem;
  float* sG1 = (float*)(smem + 4160);
  float* sG2 = (float*)(smem + 4160 + 8192);
  float (*cmb)[16][36] = (float(*)[16][36])smem;
  float (*sden)[16] = (float(*)[16])(smem + 16128);

  int bid = blockIdx.x;                // 512 = [tile(7 hi)][b(2 lo)]
  int b = bid & 3, tile = bid >> 2;
  int rowblk = tile << 4;              // 16 rows per block
  int t = threadIdx.x, lane = t & 63, w = t >> 6;  // w = j-eighth
  int cl = lane & 15, g = lane >> 4, g8 = g * 8;

  { // stage 16 rows x 64 mask words (2 per thread)
    int row = t >> 5, c = (t & 31) * 2;
    uint2 v = *(const uint2*)(mb + (size_t)(b * NN + rowblk + row) * NW + c);
    sdm[row][c + 0] = v.x; sdm[row][c + 1] = v.y;
  }
  { // stage G + block-local max of G1
    f32x4 gv = ((const f32x4*)(G1o + (size_t)b * NN))[t];
    ((f32x4*)sG1)[t] = gv;
    ((f32x4*)sG2)[t] = ((const f32x4*)(G2o + (size_t)b * NN))[t];
    float gmx = fmaxf(fmaxf(gv[0], gv[1]), fmaxf(gv[2], gv[3]));
    gmx = fmaxf(gmx, __shfl_xor(gmx, 1));  gmx = fmaxf(gmx, __shfl_xor(gmx, 2));
    gmx = fmaxf(gmx, __shfl_xor(gmx, 4));  gmx = fmaxf(gmx, __shfl_xor(gmx, 8));
    gmx = fmaxf(gmx, __shfl_xor(gmx, 16)); gmx = fmaxf(gmx, __shfl_xor(gmx, 32));
    if (lane == 0) swmax[w] = gmx;
  }
  float s = ssrc2[b * NN + rowblk + cl];
  __syncthreads();
  float mxv = fmaxf(fmaxf(fmaxf(swmax[0], swmax[1]), fmaxf(swmax[2], swmax[3])),
                    fmaxf(fmaxf(swmax[4], swmax[5]), fmaxf(swmax[6], swmax[7])));
  float logMx = __logf(mxv);
  float m = lrelu(s + logMx);
  float F1 = __expf(s - m), F2 = __expf(0.2f * s - m);

  short onev = (cl == 0) ? (short)0x3F80 : (short)0;
  bf16x8 ones = {onev, onev, onev, onev, onev, onev, onev, onev};
  f32x4 zero = {0.f, 0.f, 0.f, 0.f};
  f32x4 acc[2] = {zero, zero};
  f32x4 acc1 = zero;
  const unsigned short* fbase = wh2t + (size_t)b * 32 * NN + lane * 8;
  int kb0 = w * 8;

  bf16x8 curf[2], nxtf[2];
#pragma unroll
  for (int ft = 0; ft < 2; ++ft)
    curf[ft] = *(const bf16x8*)(fbase + (size_t)(kb0 * 2 + ft) * 512);

  for (int i = 0; i < 8; ++i) {
    int kb = kb0 + i;
    if (i < 7) {
#pragma unroll
      for (int ft = 0; ft < 2; ++ft)
        nxtf[ft] = *(const bf16x8*)(fbase + (size_t)((kb + 1) * 2 + ft) * 512);
    }
    unsigned by = (sdm[cl][kb] >> g8) & 0xFFu;
    int j0 = kb * 32 + g8;
    f32x4 g1a = *(const f32x4*)(sG1 + j0);
    f32x4 g1b = *(const f32x4*)(sG1 + j0 + 4);
    f32x4 g2a = *(const f32x4*)(sG2 + j0);
    f32x4 g2b = *(const f32x4*)(sG2 + j0 + 4);
    float wv[8];
#pragma unroll
    for (int e = 0; e < 8; ++e) {
      float g1 = (e < 4) ? g1a[e] : g1b[e - 4];
      float g2 = (e < 4) ? g2a[e] : g2b[e - 4];
      float v = fmaxf(F1 * g1, F2 * g2);
      wv[e] = ((by >> e) & 1u) ? v : 0.f;
    }
    union { unsigned u[4]; bf16x8 v; } pa;
    pa.u[0] = pk2(wv[0], wv[1]); pa.u[1] = pk2(wv[2], wv[3]);
    pa.u[2] = pk2(wv[4], wv[5]); pa.u[3] = pk2(wv[6], wv[7]);
#pragma unroll
    for (int ft = 0; ft < 2; ++ft)
      acc[ft] = __builtin_amdgcn_mfma_f32_16x16x32_bf16(pa.v, curf[ft], acc[ft], 0, 0, 0);
    acc1 = __builtin_amdgcn_mfma_f32_16x16x32_bf16(pa.v, ones, acc1, 0, 0, 0);
#pragma unroll
    for (int ft = 0; ft < 2; ++ft) curf[ft] = nxtf[ft];
  }
  __syncthreads();                     // all phase-1 LDS reads done; overlay safe
  if (w > 0) {
    int p = w - 1;
#pragma unroll
    for (int ft = 0; ft < 2; ++ft)
#pragma unroll
      for (int r = 0; r < 4; ++r)
        cmb[p][4 * g + r][ft * 16 + cl] = acc[ft][r];
    if (cl == 0) {
#pragma unroll
      for (int r = 0; r < 4; ++r) sden[p][4 * g + r] = acc1[r];
    }
  }
  __syncthreads();
  if (w == 0) {
#pragma unroll
    for (int r = 0; r < 4; ++r) {
      int rowm = 4 * g + r;
      float dself = __shfl(acc1[r], lane & 48);
      float den = dself;
#pragma unroll
      for (int p = 0; p < 7; ++p) den += sden[p][rowm];
      float inv = 1.f / den;
      float* dst = outp + (size_t)(b * NN + rowblk + rowm) * 32;
#pragma unroll
      for (int ft = 0; ft < 2; ++ft) {
        float v = acc[ft][r];
#pragma unroll
        for (int p = 0; p < 7; ++p) v += cmb[p][rowm][ft * 16 + cl];
        dst[ft * 16 + cl] = v * inv;
      }
    }
  }
}

extern "C" void kernel_launch(void* const* d_in, const int* in_sizes, int n_in,
                              void* d_out, int out_size, void* d_ws, size_t ws_size,
                              hipStream_t stream) {
  (void)in_sizes; (void)n_in; (void)out_size; (void)ws_size;
  const float* x   = (const float*)d_in[0];
  const int*   adj = (const int*)d_in[1];
  const float* W1  = (const float*)d_in[2];
  const float* a1  = (const float*)d_in[3];
  const float* W2  = (const float*)d_in[4];
  const float* a2  = (const float*)d_in[5];
  float* outp = (float*)d_out;
  char* ws = (char*)d_ws;

  unsigned*       mbits = (unsigned*)(ws);                                   // 2 MB
  unsigned short* wht1  = (unsigned short*)(ws + (size_t)(2u << 20));        // 4 MB
  float*          ssrc1 = (float*)(ws + (size_t)(6u << 20));                 // 128 KB
  float*          G1g   = (float*)(ws + (size_t)(6u << 20) + (128u << 10));  // 128 KB
  float*          G2g   = (float*)(ws + (size_t)(6u << 20) + (256u << 10));  // 128 KB
  unsigned short* hbuf  = (unsigned short*)(ws + (size_t)(6u << 20) + (512u << 10)); // 4 MB bf16
  unsigned short* wh2t  = (unsigned short*)(ws + (size_t)(14u << 20) + (512u << 10)); // 512 KB
  float*          ssrc2 = (float*)(ws + (size_t)(15u << 20));                // 32 KB
  float*          G1o   = (float*)(ws + (size_t)(15u << 20) + (32u << 10));  // 32 KB
  float*          G2o   = (float*)(ws + (size_t)(15u << 20) + (64u << 10));  // 32 KB

  kA      <<<512, 256, 0, stream>>>(x, W1, a1, wht1, ssrc1, G1g, G2g);
  k2_attn1<<<512, 512, 0, stream>>>(adj, mbits, wht1, ssrc1, G1g, G2g, hbuf);
  k3_proj2<<<512, 256, 0, stream>>>(hbuf, W2, a2, wh2t, ssrc2, G1o, G2o);
  k4_attn2<<<512, 512, 0, stream>>>(wh2t, ssrc2, G1o, G2o, mbits, outp);
}